// Round 3
// baseline (442.540 us; speedup 1.0000x reference)
//
#include <hip/hip_runtime.h>

// GAT, 2 layers, H=2 heads, D=C=128, concat=False (head mean), L2 normalize after each layer.
// Float tensors: fp32 OR bf16 (runtime-probed). edge_index: int32 OR int64 (runtime-probed).
// Output written in the probed float dtype. Internal h-matrix always bf16 (MFMA).

using short8  = __attribute__((ext_vector_type(8))) short;
using float4v = __attribute__((ext_vector_type(4))) float;

static __device__ __forceinline__ float bf2f(unsigned int u16) {
    union { unsigned int i; float f; } v; v.i = u16 << 16; return v.f;
}
static __device__ __forceinline__ float bflo(unsigned int p){ return bf2f(p & 0xffffu); }
static __device__ __forceinline__ float bfhi(unsigned int p){ return bf2f(p >> 16); }
static __device__ __forceinline__ unsigned short f2bf(float f) {
    union { float f; unsigned int i; } v; v.f = f;
    unsigned int x = v.i;
    x += 0x7fffu + ((x >> 16) & 1u);   // RNE
    return (unsigned short)(x >> 16);
}
static __device__ __forceinline__ float leaky(float x){ return x > 0.f ? x : 0.2f * x; }

// ---------------- dtype probes ----------------
// flags[0]=1 iff x is fp32 (low-half-as-bf16 exponent >= 2^27 seen)
// flags[1]=1 iff edge_index is int64 (all odd 32-bit words zero)
__global__ __launch_bounds__(256) void k_probe(const unsigned int* __restrict__ xw,
                                               const int* __restrict__ ei,
                                               int* __restrict__ flags) {
    __shared__ int insane, oddnz;
    int t = threadIdx.x;
    if (t == 0) { insane = 0; oddnz = 0; }
    __syncthreads();
    unsigned int w = xw[t];
    if (((w >> 7) & 0xFFu) >= 154u) atomicOr(&insane, 1);
    if (ei[2 * t + 1] != 0) atomicOr(&oddnz, 1);
    __syncthreads();
    if (t == 0) { flags[0] = insane ? 1 : 0; flags[1] = oddnz ? 0 : 1; }
}

// ---------------- W -> WT (bf16): WT[l][n][k] = W[l][k][n] ----------------
__global__ __launch_bounds__(256) void k_transpose(const void* __restrict__ W,
                                                   unsigned short* __restrict__ WT,
                                                   const int* __restrict__ flags) {
    int fx = flags[0];
    int idx = blockIdx.x * 256 + threadIdx.x;      // 0 .. 2*128*256-1
    int layer = idx >> 15;
    int rem = idx & 32767;
    int k = rem >> 8, n = rem & 255;
    int srci = layer * 32768 + k * 256 + n;
    unsigned short v;
    if (fx) v = f2bf(((const float*)W)[srci]);
    else    v = ((const unsigned short*)W)[srci];
    WT[layer * 32768 + n * 128 + k] = v;
}

// ---------------- GEMM: Hb[N][256] = X[N][128] @ W[128][256], MFMA 16x16x32 bf16 ----------------
__global__ __launch_bounds__(256) void k_gemm(const void* __restrict__ X,
                                              const unsigned short* __restrict__ WT,
                                              unsigned short* __restrict__ Hb, int N,
                                              const int* __restrict__ flags) {
    int fx = flags[0];
    int mt = blockIdx.x * 4 + (threadIdx.x >> 6);
    int mtiles = (N + 15) >> 4;
    if (mt >= mtiles) return;
    int lane = threadIdx.x & 63;
    int r16 = lane & 15, quad = lane >> 4;
    int m0 = mt << 4;
    int arow = m0 + r16; if (arow >= N) arow = N - 1;
    short8 a[4];
    if (fx) {
        const float* Xf = (const float*)X;
#pragma unroll
        for (int kk = 0; kk < 4; kk++) {
            const float4v* pv = (const float4v*)(Xf + (size_t)arow * 128 + kk * 32 + quad * 8);
            float4v lo = pv[0], hi = pv[1];
            short8 t;
            t[0] = (short)f2bf(lo[0]); t[1] = (short)f2bf(lo[1]);
            t[2] = (short)f2bf(lo[2]); t[3] = (short)f2bf(lo[3]);
            t[4] = (short)f2bf(hi[0]); t[5] = (short)f2bf(hi[1]);
            t[6] = (short)f2bf(hi[2]); t[7] = (short)f2bf(hi[3]);
            a[kk] = t;
        }
    } else {
        const unsigned short* Xh = (const unsigned short*)X;
#pragma unroll
        for (int kk = 0; kk < 4; kk++)
            a[kk] = *(const short8*)(Xh + (size_t)arow * 128 + kk * 32 + quad * 8);
    }
#pragma unroll
    for (int nt = 0; nt < 16; nt++) {
        float4v acc = {0.f, 0.f, 0.f, 0.f};
#pragma unroll
        for (int kk = 0; kk < 4; kk++) {
            short8 b = *(const short8*)(WT + (nt * 16 + r16) * 128 + kk * 32 + quad * 8);
            acc = __builtin_amdgcn_mfma_f32_16x16x32_bf16(a[kk], b, acc, 0, 0, 0);
        }
        int col = nt * 16 + r16;
#pragma unroll
        for (int r = 0; r < 4; r++) {
            int row = m0 + quad * 4 + r;           // C/D: col=lane&15, row=quad*4+reg  [m89]
            if (row < N) Hb[(size_t)row * 256 + col] = f2bf(acc[r]);
        }
    }
}

// ---------------- alpha_src / alpha_dst per (node, head) ----------------
__global__ __launch_bounds__(256) void k_alpha(const unsigned short* __restrict__ Hb,
                                               const void* __restrict__ atts,
                                               const void* __restrict__ attd,
                                               int layer, const int* __restrict__ flags,
                                               float* __restrict__ as_, float* __restrict__ ad_, int N) {
    int fx = flags[0];
    int n = blockIdx.x * 4 + (threadIdx.x >> 6);
    if (n >= N) return;
    int lane = threadIdx.x & 63;
    uint2 hv = *(const uint2*)(Hb + (size_t)n * 256 + lane * 4);
    float h0 = bflo(hv.x), h1 = bfhi(hv.x), h2 = bflo(hv.y), h3 = bfhi(hv.y);
    int off = layer * 256 + lane * 4;
    float s0, s1, s2, s3, d0, d1, d2, d3;
    if (fx) {
        float4v sv = *(const float4v*)((const float*)atts + off);
        float4v dv = *(const float4v*)((const float*)attd + off);
        s0 = sv[0]; s1 = sv[1]; s2 = sv[2]; s3 = sv[3];
        d0 = dv[0]; d1 = dv[1]; d2 = dv[2]; d3 = dv[3];
    } else {
        uint2 sv = *(const uint2*)((const unsigned short*)atts + off);
        uint2 dv = *(const uint2*)((const unsigned short*)attd + off);
        s0 = bflo(sv.x); s1 = bfhi(sv.x); s2 = bflo(sv.y); s3 = bfhi(sv.y);
        d0 = bflo(dv.x); d1 = bfhi(dv.x); d2 = bflo(dv.y); d3 = bfhi(dv.y);
    }
    float s = h0 * s0 + h1 * s1 + h2 * s2 + h3 * s3;
    float d = h0 * d0 + h1 * d1 + h2 * d2 + h3 * d3;
#pragma unroll
    for (int m = 1; m <= 16; m <<= 1) { s += __shfl_xor(s, m); d += __shfl_xor(d, m); }
    if (lane == 0)       { as_[2 * n]     = s; ad_[2 * n]     = d; }  // head 0 (lanes 0..31)
    else if (lane == 32) { as_[2 * n + 1] = s; ad_[2 * n + 1] = d; }  // head 1 (lanes 32..63)
}

// ---------------- CSR build ----------------
static __device__ __forceinline__ int edge_dst(const int* ei, int E, int i, int is64) {
    return is64 ? ei[2 * E + 2 * i] : ei[E + i];
}
static __device__ __forceinline__ int edge_src(const int* ei, int E, int i, int is64) {
    return is64 ? ei[2 * i] : ei[i];
}

__global__ __launch_bounds__(256) void k_count(const int* __restrict__ ei, int E, int N,
                                               const int* __restrict__ flags, int* deg) {
    int i = blockIdx.x * 256 + threadIdx.x;
    if (i >= E + N) return;
    int dst;
    if (i < E) { dst = edge_dst(ei, E, i, flags[1]); if ((unsigned)dst >= (unsigned)N) dst = 0; }
    else dst = i - E;   // self loops appended
    atomicAdd(&deg[dst], 1);
}

__global__ __launch_bounds__(1024) void k_scan1(const int* __restrict__ deg, int* __restrict__ excl,
                                                int* __restrict__ bsum, int n) {
    __shared__ int buf[1024];
    int t = threadIdx.x;
    int i = blockIdx.x * 1024 + t;
    int v = (i < n) ? deg[i] : 0;
    int x = v; buf[t] = v; __syncthreads();
    for (int off = 1; off < 1024; off <<= 1) {
        int add = (t >= off) ? buf[t - off] : 0;
        __syncthreads();
        x += add; buf[t] = x;
        __syncthreads();
    }
    if (i < n) excl[i] = x - v;
    if (t == 1023) bsum[blockIdx.x] = x;
}

__global__ __launch_bounds__(256) void k_scan2(int* bsum, int nb) {
    __shared__ int buf[256];
    int t = threadIdx.x;
    int v = (t < nb) ? bsum[t] : 0;
    int x = v; buf[t] = v; __syncthreads();
    for (int off = 1; off < 256; off <<= 1) {
        int add = (t >= off) ? buf[t - off] : 0;
        __syncthreads();
        x += add; buf[t] = x;
        __syncthreads();
    }
    if (t < nb) bsum[t] = x - v;
    if (t == nb - 1) bsum[nb] = x;   // grand total
}

__global__ __launch_bounds__(256) void k_scan3(int* __restrict__ rowptr, const int* __restrict__ bsum, int N) {
    int i = blockIdx.x * 256 + threadIdx.x;
    if (i < N) rowptr[i] += bsum[i >> 10];
    else if (i == N) rowptr[N] = bsum[(N + 1023) >> 10];
}

__global__ __launch_bounds__(256) void k_cursor(const int* __restrict__ rowptr, int* __restrict__ cursor, int N) {
    int i = blockIdx.x * 256 + threadIdx.x;
    if (i < N) cursor[i] = rowptr[i];
}

__global__ __launch_bounds__(256) void k_scatter(const int* __restrict__ ei, int E, int N,
                                                 const int* __restrict__ flags,
                                                 int* __restrict__ cursor, int* __restrict__ csr) {
    int i = blockIdx.x * 256 + threadIdx.x;
    if (i >= E + N) return;
    int src, dst;
    if (i < E) {
        int is64 = flags[1];
        src = edge_src(ei, E, i, is64);
        dst = edge_dst(ei, E, i, is64);
        if ((unsigned)src >= (unsigned)N) src = 0;
        if ((unsigned)dst >= (unsigned)N) dst = 0;
    } else src = dst = i - E;
    int pos = atomicAdd(&cursor[dst], 1);
    csr[pos] = src;
}

// ---------------- per-dst softmax + aggregation + head-mean + bias + L2 norm ----------------
__global__ __launch_bounds__(256) void k_aggregate(const unsigned short* __restrict__ Hb,
                                                   const float* __restrict__ as_, const float* __restrict__ ad_,
                                                   const int* __restrict__ rowptr, const int* __restrict__ csr,
                                                   const void* __restrict__ bias, int layer,
                                                   const int* __restrict__ flags,
                                                   void* __restrict__ outp, int N, int EL) {
    int fx = flags[0];
    int n = blockIdx.x * 4 + (threadIdx.x >> 6);
    if (n >= N) return;
    int lane = threadIdx.x & 63;
    int start = rowptr[n], end = rowptr[n + 1];
    if (start < 0) start = 0;
    if (end > EL) end = EL;
    if (end < start) end = start;
    float ad0 = ad_[2 * n], ad1 = ad_[2 * n + 1];

    // pass 1: segment max
    float m0 = -1e30f, m1 = -1e30f;
    for (int i = start + lane; i < end; i += 64) {
        int s = csr[i]; if ((unsigned)s >= (unsigned)N) s = 0;
        float l0 = leaky(as_[2 * s] + ad0);
        float l1 = leaky(as_[2 * s + 1] + ad1);
        m0 = fmaxf(m0, l0); m1 = fmaxf(m1, l1);
    }
#pragma unroll
    for (int m = 1; m < 64; m <<= 1) { m0 = fmaxf(m0, __shfl_xor(m0, m)); m1 = fmaxf(m1, __shfl_xor(m1, m)); }

    // pass 2: segment sum of exp
    float z0 = 0.f, z1 = 0.f;
    for (int i = start + lane; i < end; i += 64) {
        int s = csr[i]; if ((unsigned)s >= (unsigned)N) s = 0;
        float l0 = leaky(as_[2 * s] + ad0);
        float l1 = leaky(as_[2 * s + 1] + ad1);
        z0 += __expf(l0 - m0); z1 += __expf(l1 - m1);
    }
#pragma unroll
    for (int m = 1; m < 64; m <<= 1) { z0 += __shfl_xor(z0, m); z1 += __shfl_xor(z1, m); }
    float inv0 = 1.f / (z0 + 1e-16f), inv1 = 1.f / (z1 + 1e-16f);

    // pass 3: weighted feature accumulation
    float a00 = 0.f, a01 = 0.f, a10 = 0.f, a11 = 0.f;
    int c0 = lane * 2;
    for (int t = start; t < end; t += 64) {
        int i = t + lane; int s = 0; float w0 = 0.f, w1 = 0.f;
        if (i < end) {
            s = csr[i]; if ((unsigned)s >= (unsigned)N) s = 0;
            float l0 = leaky(as_[2 * s] + ad0);
            float l1 = leaky(as_[2 * s + 1] + ad1);
            w0 = __expf(l0 - m0) * inv0;
            w1 = __expf(l1 - m1) * inv1;
        }
        int cnt = end - t; if (cnt > 64) cnt = 64;
        for (int q = 0; q < cnt; q++) {
            int sq    = __shfl(s, q);
            float wq0 = __shfl(w0, q);
            float wq1 = __shfl(w1, q);
            unsigned int p0 = *(const unsigned int*)(Hb + (size_t)sq * 256 + c0);         // head 0
            unsigned int p1 = *(const unsigned int*)(Hb + (size_t)sq * 256 + 128 + c0);   // head 1
            a00 += wq0 * bflo(p0); a01 += wq0 * bfhi(p0);
            a10 += wq1 * bflo(p1); a11 += wq1 * bfhi(p1);
        }
    }

    // head mean + bias
    float b0, b1;
    if (fx) {
        const float* bf = (const float*)bias + layer * 128 + c0;
        b0 = bf[0]; b1 = bf[1];
    } else {
        unsigned int bv = *(const unsigned int*)((const unsigned short*)bias + layer * 128 + c0);
        b0 = bflo(bv); b1 = bfhi(bv);
    }
    float v0 = 0.5f * (a00 + a10) + b0;
    float v1 = 0.5f * (a01 + a11) + b1;

    // L2 normalize across 128 channels
    float ss = v0 * v0 + v1 * v1;
#pragma unroll
    for (int m = 1; m < 64; m <<= 1) ss += __shfl_xor(ss, m);
    float inv = 1.f / fmaxf(sqrtf(ss), 1e-12f);
    if (fx) {
        float2 o; o.x = v0 * inv; o.y = v1 * inv;
        *(float2*)((float*)outp + (size_t)n * 128 + c0) = o;
    } else {
        unsigned int pk = (unsigned int)f2bf(v0 * inv) | ((unsigned int)f2bf(v1 * inv) << 16);
        *(unsigned int*)((unsigned short*)outp + (size_t)n * 128 + c0) = pk;
    }
}

extern "C" void kernel_launch(void* const* d_in, const int* in_sizes, int n_in,
                              void* d_out, int out_size, void* d_ws, size_t ws_size,
                              hipStream_t stream) {
    const void* x    = d_in[0];               // [N,128] fp32 or bf16
    const int*  ei   = (const int*)d_in[1];   // [2,E] int32 or int64
    const void* W    = d_in[2];               // [2,128,256]
    const void* atts = d_in[3];               // [2,2,128]
    const void* attd = d_in[4];               // [2,2,128]
    const void* bias = d_in[5];               // [2,128]

    int N = in_sizes[0] / 128;
    int E = in_sizes[1] / 2;
    int EL = E + N;

    char* p = (char*)d_ws;
    auto alloc = [&](size_t bytes) -> char* {
        char* q = p; p += (bytes + 255) & ~(size_t)255; return q;
    };
    // small-first packing; total ~30.4 MB
    int* flags   = (int*)alloc(256);
    int* bsum    = (int*)alloc(2048 * 4);
    int* rowptr  = (int*)alloc((size_t)(N + 1) * 4);
    int* cursor  = (int*)alloc((size_t)N * 4);
    float* as_   = (float*)alloc((size_t)N * 2 * 4);
    float* ad_   = (float*)alloc((size_t)N * 2 * 4);
    unsigned short* wt = (unsigned short*)alloc(2 * 256 * 128 * 2);
    int* csr     = (int*)alloc((size_t)EL * 4);
    unsigned short* hbuf = (unsigned short*)alloc((size_t)N * 256 * 2);   // 25.6 MB, last

    k_probe<<<1, 256, 0, stream>>>((const unsigned int*)x, ei, flags);

    // CSR by dst (rebuilt every call — no static state)
    hipMemsetAsync(cursor, 0, (size_t)N * 4, stream);
    k_count<<<(EL + 255) / 256, 256, 0, stream>>>(ei, E, N, flags, cursor);
    int nb = (N + 1023) / 1024;
    k_scan1<<<nb, 1024, 0, stream>>>(cursor, rowptr, bsum, N);
    k_scan2<<<1, 256, 0, stream>>>(bsum, nb);
    k_scan3<<<(N + 256) / 256, 256, 0, stream>>>(rowptr, bsum, N);
    k_cursor<<<(N + 255) / 256, 256, 0, stream>>>(rowptr, cursor, N);
    k_scatter<<<(EL + 255) / 256, 256, 0, stream>>>(ei, E, N, flags, cursor, csr);

    k_transpose<<<256, 256, 0, stream>>>(W, wt, flags);

    int mtiles = (N + 15) / 16;
    for (int l = 0; l < 2; l++) {
        const void* xin = (l == 0) ? x : (const void*)d_out;  // layer 1 reads layer-0 output (same dtype)
        k_gemm<<<(mtiles + 3) / 4, 256, 0, stream>>>(xin, wt + l * 32768, hbuf, N, flags);
        k_alpha<<<(N + 3) / 4, 256, 0, stream>>>(hbuf, atts, attd, l, flags, as_, ad_, N);
        k_aggregate<<<(N + 3) / 4, 256, 0, stream>>>(hbuf, as_, ad_, rowptr, csr, bias, l, flags,
                                                     d_out, N, EL);
    }
}

// Round 4
// 411.765 us; speedup vs baseline: 1.0747x; 1.0747x over previous
//
#include <hip/hip_runtime.h>

// GAT, 2 layers, H=2 heads, D=C=128, concat=False (head mean), L2 normalize after each layer.
// Float tensors: fp32 OR bf16 (runtime-probed). edge_index: int32 OR int64 (runtime-probed).
// Output written in the probed float dtype. Internal h-matrix always bf16 (MFMA).

using short8  = __attribute__((ext_vector_type(8))) short;
using float4v = __attribute__((ext_vector_type(4))) float;

static __device__ __forceinline__ float bf2f(unsigned int u16) {
    union { unsigned int i; float f; } v; v.i = u16 << 16; return v.f;
}
static __device__ __forceinline__ float bflo(unsigned int p){  // low bf16 -> f32 (1 shift)
    union { unsigned int i; float f; } v; v.i = p << 16; return v.f;
}
static __device__ __forceinline__ float bfhi(unsigned int p){  // high bf16 -> f32 (1 and)
    union { unsigned int i; float f; } v; v.i = p & 0xffff0000u; return v.f;
}
static __device__ __forceinline__ unsigned short f2bf(float f) {
    union { float f; unsigned int i; } v; v.f = f;
    unsigned int x = v.i;
    x += 0x7fffu + ((x >> 16) & 1u);   // RNE
    return (unsigned short)(x >> 16);
}
static __device__ __forceinline__ float leaky(float x){ return x > 0.f ? x : 0.2f * x; }

// ---------------- dtype probes ----------------
// flags[0]=1 iff x is fp32 (low-half-as-bf16 exponent >= 2^27 seen)
// flags[1]=1 iff edge_index is int64 (all odd 32-bit words zero)
__global__ __launch_bounds__(256) void k_probe(const unsigned int* __restrict__ xw,
                                               const int* __restrict__ ei,
                                               int* __restrict__ flags) {
    __shared__ int insane, oddnz;
    int t = threadIdx.x;
    if (t == 0) { insane = 0; oddnz = 0; }
    __syncthreads();
    unsigned int w = xw[t];
    if (((w >> 7) & 0xFFu) >= 154u) atomicOr(&insane, 1);
    if (ei[2 * t + 1] != 0) atomicOr(&oddnz, 1);
    __syncthreads();
    if (t == 0) { flags[0] = insane ? 1 : 0; flags[1] = oddnz ? 0 : 1; }
}

// ---------------- W -> WT (bf16): WT[l][n][k] = W[l][k][n] ----------------
__global__ __launch_bounds__(256) void k_transpose(const void* __restrict__ W,
                                                   unsigned short* __restrict__ WT,
                                                   const int* __restrict__ flags) {
    int fx = flags[0];
    int idx = blockIdx.x * 256 + threadIdx.x;      // 0 .. 2*128*256-1
    int layer = idx >> 15;
    int rem = idx & 32767;
    int k = rem >> 8, n = rem & 255;
    int srci = layer * 32768 + k * 256 + n;
    unsigned short v;
    if (fx) v = f2bf(((const float*)W)[srci]);
    else    v = ((const unsigned short*)W)[srci];
    WT[layer * 32768 + n * 128 + k] = v;
}

// ---------------- GEMM: Hb[N][256] = X[N][128] @ W[128][256], MFMA 16x16x32 bf16 ----------------
// one block per 16-row M-tile; wave w computes col tiles [4w, 4w+4). 3125 blocks -> ~32 waves/CU.
__global__ __launch_bounds__(256) void k_gemm(const void* __restrict__ X,
                                              const unsigned short* __restrict__ WT,
                                              unsigned short* __restrict__ Hb, int N,
                                              const int* __restrict__ flags) {
    int fx = flags[0];
    int mt = blockIdx.x;
    int wave = threadIdx.x >> 6;
    int lane = threadIdx.x & 63;
    int r16 = lane & 15, quad = lane >> 4;
    int m0 = mt << 4;
    int arow = m0 + r16; if (arow >= N) arow = N - 1;
    short8 a[4];
    if (fx) {
        const float* Xf = (const float*)X;
#pragma unroll
        for (int kk = 0; kk < 4; kk++) {
            const float4v* pv = (const float4v*)(Xf + (size_t)arow * 128 + kk * 32 + quad * 8);
            float4v lo = pv[0], hi = pv[1];
            short8 t;
            t[0] = (short)f2bf(lo[0]); t[1] = (short)f2bf(lo[1]);
            t[2] = (short)f2bf(lo[2]); t[3] = (short)f2bf(lo[3]);
            t[4] = (short)f2bf(hi[0]); t[5] = (short)f2bf(hi[1]);
            t[6] = (short)f2bf(hi[2]); t[7] = (short)f2bf(hi[3]);
            a[kk] = t;
        }
    } else {
        const unsigned short* Xh = (const unsigned short*)X;
#pragma unroll
        for (int kk = 0; kk < 4; kk++)
            a[kk] = *(const short8*)(Xh + (size_t)arow * 128 + kk * 32 + quad * 8);
    }
#pragma unroll
    for (int nn = 0; nn < 4; nn++) {
        int nt = wave * 4 + nn;
        float4v acc = {0.f, 0.f, 0.f, 0.f};
#pragma unroll
        for (int kk = 0; kk < 4; kk++) {
            short8 b = *(const short8*)(WT + (nt * 16 + r16) * 128 + kk * 32 + quad * 8);
            acc = __builtin_amdgcn_mfma_f32_16x16x32_bf16(a[kk], b, acc, 0, 0, 0);
        }
        int col = nt * 16 + r16;
#pragma unroll
        for (int r = 0; r < 4; r++) {
            int row = m0 + quad * 4 + r;           // C/D: col=lane&15, row=quad*4+reg  [m89]
            if (row < N) Hb[(size_t)row * 256 + col] = f2bf(acc[r]);
        }
    }
}

// ---------------- alpha_src / alpha_dst per (node, head) ----------------
__global__ __launch_bounds__(256) void k_alpha(const unsigned short* __restrict__ Hb,
                                               const void* __restrict__ atts,
                                               const void* __restrict__ attd,
                                               int layer, const int* __restrict__ flags,
                                               float* __restrict__ as_, float* __restrict__ ad_, int N) {
    int fx = flags[0];
    int n = blockIdx.x * 4 + (threadIdx.x >> 6);
    if (n >= N) return;
    int lane = threadIdx.x & 63;
    uint2 hv = *(const uint2*)(Hb + (size_t)n * 256 + lane * 4);
    float h0 = bflo(hv.x), h1 = bfhi(hv.x), h2 = bflo(hv.y), h3 = bfhi(hv.y);
    int off = layer * 256 + lane * 4;
    float s0, s1, s2, s3, d0, d1, d2, d3;
    if (fx) {
        float4v sv = *(const float4v*)((const float*)atts + off);
        float4v dv = *(const float4v*)((const float*)attd + off);
        s0 = sv[0]; s1 = sv[1]; s2 = sv[2]; s3 = sv[3];
        d0 = dv[0]; d1 = dv[1]; d2 = dv[2]; d3 = dv[3];
    } else {
        uint2 sv = *(const uint2*)((const unsigned short*)atts + off);
        uint2 dv = *(const uint2*)((const unsigned short*)attd + off);
        s0 = bflo(sv.x); s1 = bfhi(sv.x); s2 = bflo(sv.y); s3 = bfhi(sv.y);
        d0 = bflo(dv.x); d1 = bfhi(dv.x); d2 = bflo(dv.y); d3 = bfhi(dv.y);
    }
    float s = h0 * s0 + h1 * s1 + h2 * s2 + h3 * s3;
    float d = h0 * d0 + h1 * d1 + h2 * d2 + h3 * d3;
#pragma unroll
    for (int m = 1; m <= 16; m <<= 1) { s += __shfl_xor(s, m); d += __shfl_xor(d, m); }
    if (lane == 0)       { as_[2 * n]     = s; ad_[2 * n]     = d; }  // head 0 (lanes 0..31)
    else if (lane == 32) { as_[2 * n + 1] = s; ad_[2 * n + 1] = d; }  // head 1 (lanes 32..63)
}

// ---------------- CSR build ----------------
static __device__ __forceinline__ int edge_dst(const int* ei, int E, int i, int is64) {
    return is64 ? ei[2 * E + 2 * i] : ei[E + i];
}
static __device__ __forceinline__ int edge_src(const int* ei, int E, int i, int is64) {
    return is64 ? ei[2 * i] : ei[i];
}

__global__ __launch_bounds__(256) void k_count(const int* __restrict__ ei, int E, int N,
                                               const int* __restrict__ flags, int* deg) {
    int i = blockIdx.x * 256 + threadIdx.x;
    if (i >= E + N) return;
    int dst;
    if (i < E) { dst = edge_dst(ei, E, i, flags[1]); if ((unsigned)dst >= (unsigned)N) dst = 0; }
    else dst = i - E;   // self loops appended
    atomicAdd(&deg[dst], 1);
}

__global__ __launch_bounds__(1024) void k_scan1(const int* __restrict__ deg, int* __restrict__ excl,
                                                int* __restrict__ bsum, int n) {
    __shared__ int buf[1024];
    int t = threadIdx.x;
    int i = blockIdx.x * 1024 + t;
    int v = (i < n) ? deg[i] : 0;
    int x = v; buf[t] = v; __syncthreads();
    for (int off = 1; off < 1024; off <<= 1) {
        int add = (t >= off) ? buf[t - off] : 0;
        __syncthreads();
        x += add; buf[t] = x;
        __syncthreads();
    }
    if (i < n) excl[i] = x - v;
    if (t == 1023) bsum[blockIdx.x] = x;
}

__global__ __launch_bounds__(256) void k_scan2(int* bsum, int nb) {
    __shared__ int buf[256];
    int t = threadIdx.x;
    int v = (t < nb) ? bsum[t] : 0;
    int x = v; buf[t] = v; __syncthreads();
    for (int off = 1; off < 256; off <<= 1) {
        int add = (t >= off) ? buf[t - off] : 0;
        __syncthreads();
        x += add; buf[t] = x;
        __syncthreads();
    }
    if (t < nb) bsum[t] = x - v;
    if (t == nb - 1) bsum[nb] = x;   // grand total
}

__global__ __launch_bounds__(256) void k_scan3(int* __restrict__ rowptr, const int* __restrict__ bsum, int N) {
    int i = blockIdx.x * 256 + threadIdx.x;
    if (i < N) rowptr[i] += bsum[i >> 10];
    else if (i == N) rowptr[N] = bsum[(N + 1023) >> 10];
}

__global__ __launch_bounds__(256) void k_cursor(const int* __restrict__ rowptr, int* __restrict__ cursor, int N) {
    int i = blockIdx.x * 256 + threadIdx.x;
    if (i < N) cursor[i] = rowptr[i];
}

__global__ __launch_bounds__(256) void k_scatter(const int* __restrict__ ei, int E, int N,
                                                 const int* __restrict__ flags,
                                                 int* __restrict__ cursor, int* __restrict__ csr) {
    int i = blockIdx.x * 256 + threadIdx.x;
    if (i >= E + N) return;
    int src, dst;
    if (i < E) {
        int is64 = flags[1];
        src = edge_src(ei, E, i, is64);
        dst = edge_dst(ei, E, i, is64);
        if ((unsigned)src >= (unsigned)N) src = 0;
        if ((unsigned)dst >= (unsigned)N) dst = 0;
    } else src = dst = i - E;
    int pos = atomicAdd(&cursor[dst], 1);
    csr[pos] = src;
}

// ---------------- per-dst softmax + aggregation + head-mean + bias + L2 norm ----------------
// one wave per node. 4 lane-groups of 16 each gather one edge (2x dwordx4/lane, 512B/edge),
// 4 edges in flight; z-sum fused into the gather pass (unnormalized acc, scaled at end).
static __device__ __forceinline__ void acc8(float* A, float w, uint4 q) {
    A[0] += w * bflo(q.x); A[1] += w * bfhi(q.x);
    A[2] += w * bflo(q.y); A[3] += w * bfhi(q.y);
    A[4] += w * bflo(q.z); A[5] += w * bfhi(q.z);
    A[6] += w * bflo(q.w); A[7] += w * bfhi(q.w);
}

__global__ __launch_bounds__(256) void k_aggregate(const unsigned short* __restrict__ Hb,
                                                   const float* __restrict__ as_, const float* __restrict__ ad_,
                                                   const int* __restrict__ rowptr, const int* __restrict__ csr,
                                                   const void* __restrict__ bias, int layer,
                                                   const int* __restrict__ flags,
                                                   void* __restrict__ outp, int N, int EL) {
    int fx = flags[0];
    int n = blockIdx.x * 4 + (threadIdx.x >> 6);
    if (n >= N) return;
    int lane = threadIdx.x & 63;
    int g = lane >> 4;       // group 0..3
    int gl = lane & 15;      // lane within group; owns channels [gl*8, gl*8+8) of each head
    int start = rowptr[n], end = rowptr[n + 1];
    if (start < 0) start = 0;
    if (end > EL) end = EL;
    if (end < start) end = start;
    float ad0 = ad_[2 * n], ad1 = ad_[2 * n + 1];

    // pass 1: segment max (lane-parallel)
    float m0 = -1e30f, m1 = -1e30f;
    for (int i = start + lane; i < end; i += 64) {
        int s = csr[i]; if ((unsigned)s >= (unsigned)N) s = 0;
        m0 = fmaxf(m0, leaky(as_[2 * s] + ad0));
        m1 = fmaxf(m1, leaky(as_[2 * s + 1] + ad1));
    }
#pragma unroll
    for (int m = 1; m < 64; m <<= 1) { m0 = fmaxf(m0, __shfl_xor(m0, m)); m1 = fmaxf(m1, __shfl_xor(m1, m)); }

    // pass 2 (fused): unnormalized accumulate + z-sum
    float acc0[8] = {0,0,0,0,0,0,0,0}, acc1[8] = {0,0,0,0,0,0,0,0};
    float z0 = 0.f, z1 = 0.f;
    for (int t = start; t < end; t += 64) {
        int i = t + lane;
        int s = 0; float w0 = 0.f, w1 = 0.f;
        if (i < end) {
            s = csr[i]; if ((unsigned)s >= (unsigned)N) s = 0;
            w0 = __expf(leaky(as_[2 * s] + ad0) - m0);
            w1 = __expf(leaky(as_[2 * s + 1] + ad1) - m1);
            z0 += w0; z1 += w1;
        }
        int cnt = end - t; if (cnt > 64) cnt = 64;
        for (int j = 0; 4 * j < cnt; j++) {
            int e = 4 * j + g;                    // this group's edge slot in the chunk
            int sq    = __shfl(s, e);
            float wq0 = __shfl(w0, e);
            float wq1 = __shfl(w1, e);
            if (e < cnt) {
                const unsigned short* row = Hb + ((size_t)sq << 8);
                uint4 q0 = *(const uint4*)(row + gl * 8);          // head 0, 8 ch
                uint4 q1 = *(const uint4*)(row + 128 + gl * 8);    // head 1, 8 ch
                acc8(acc0, wq0, q0);
                acc8(acc1, wq1, q1);
            }
        }
    }
    // z across all 64 lanes
#pragma unroll
    for (int m = 1; m < 64; m <<= 1) { z0 += __shfl_xor(z0, m); z1 += __shfl_xor(z1, m); }
    float inv0 = 1.f / (z0 + 1e-16f), inv1 = 1.f / (z1 + 1e-16f);
    // acc across the 4 groups (lanes g*16+gl all hold partials for channel set gl)
#pragma unroll
    for (int k = 0; k < 8; k++) {
        acc0[k] += __shfl_xor(acc0[k], 16); acc0[k] += __shfl_xor(acc0[k], 32);
        acc1[k] += __shfl_xor(acc1[k], 16); acc1[k] += __shfl_xor(acc1[k], 32);
    }

    // head mean + bias (channels gl*8 .. gl*8+8)
    float v[8];
    if (fx) {
        const float* bf = (const float*)bias + layer * 128 + gl * 8;
#pragma unroll
        for (int k = 0; k < 8; k++) v[k] = 0.5f * (acc0[k] * inv0 + acc1[k] * inv1) + bf[k];
    } else {
        const unsigned short* bh = (const unsigned short*)bias + layer * 128 + gl * 8;
        uint4 bv = *(const uint4*)bh;
        float bfv[8] = { bflo(bv.x), bfhi(bv.x), bflo(bv.y), bfhi(bv.y),
                         bflo(bv.z), bfhi(bv.z), bflo(bv.w), bfhi(bv.w) };
#pragma unroll
        for (int k = 0; k < 8; k++) v[k] = 0.5f * (acc0[k] * inv0 + acc1[k] * inv1) + bfv[k];
    }

    // L2 normalize over 128 channels (reduce within 16-lane group)
    float ss = 0.f;
#pragma unroll
    for (int k = 0; k < 8; k++) ss += v[k] * v[k];
#pragma unroll
    for (int m = 1; m < 16; m <<= 1) ss += __shfl_xor(ss, m);
    float inv = 1.f / fmaxf(sqrtf(ss), 1e-12f);

    if (lane < 16) {   // group 0 writes; channels gl*8..gl*8+8
        if (fx) {
            float* op = (float*)outp + (size_t)n * 128 + gl * 8;
            float4 o0 = { v[0] * inv, v[1] * inv, v[2] * inv, v[3] * inv };
            float4 o1 = { v[4] * inv, v[5] * inv, v[6] * inv, v[7] * inv };
            *(float4*)op = o0;
            *(float4*)(op + 4) = o1;
        } else {
            unsigned short* op = (unsigned short*)outp + (size_t)n * 128 + gl * 8;
            uint4 pk;
            pk.x = (unsigned int)f2bf(v[0] * inv) | ((unsigned int)f2bf(v[1] * inv) << 16);
            pk.y = (unsigned int)f2bf(v[2] * inv) | ((unsigned int)f2bf(v[3] * inv) << 16);
            pk.z = (unsigned int)f2bf(v[4] * inv) | ((unsigned int)f2bf(v[5] * inv) << 16);
            pk.w = (unsigned int)f2bf(v[6] * inv) | ((unsigned int)f2bf(v[7] * inv) << 16);
            *(uint4*)op = pk;
        }
    }
}

extern "C" void kernel_launch(void* const* d_in, const int* in_sizes, int n_in,
                              void* d_out, int out_size, void* d_ws, size_t ws_size,
                              hipStream_t stream) {
    const void* x    = d_in[0];               // [N,128] fp32 or bf16
    const int*  ei   = (const int*)d_in[1];   // [2,E] int32 or int64
    const void* W    = d_in[2];               // [2,128,256]
    const void* atts = d_in[3];               // [2,2,128]
    const void* attd = d_in[4];               // [2,2,128]
    const void* bias = d_in[5];               // [2,128]

    int N = in_sizes[0] / 128;
    int E = in_sizes[1] / 2;
    int EL = E + N;

    char* p = (char*)d_ws;
    auto alloc = [&](size_t bytes) -> char* {
        char* q = p; p += (bytes + 255) & ~(size_t)255; return q;
    };
    // small-first packing; total ~30.4 MB
    int* flags   = (int*)alloc(256);
    int* bsum    = (int*)alloc(2048 * 4);
    int* rowptr  = (int*)alloc((size_t)(N + 1) * 4);
    int* cursor  = (int*)alloc((size_t)N * 4);
    float* as_   = (float*)alloc((size_t)N * 2 * 4);
    float* ad_   = (float*)alloc((size_t)N * 2 * 4);
    unsigned short* wt = (unsigned short*)alloc(2 * 256 * 128 * 2);
    int* csr     = (int*)alloc((size_t)EL * 4);
    unsigned short* hbuf = (unsigned short*)alloc((size_t)N * 256 * 2);   // 25.6 MB, last

    k_probe<<<1, 256, 0, stream>>>((const unsigned int*)x, ei, flags);

    // CSR by dst (rebuilt every call — no static state)
    hipMemsetAsync(cursor, 0, (size_t)N * 4, stream);
    k_count<<<(EL + 255) / 256, 256, 0, stream>>>(ei, E, N, flags, cursor);
    int nb = (N + 1023) / 1024;
    k_scan1<<<nb, 1024, 0, stream>>>(cursor, rowptr, bsum, N);
    k_scan2<<<1, 256, 0, stream>>>(bsum, nb);
    k_scan3<<<(N + 256) / 256, 256, 0, stream>>>(rowptr, bsum, N);
    k_cursor<<<(N + 255) / 256, 256, 0, stream>>>(rowptr, cursor, N);
    k_scatter<<<(EL + 255) / 256, 256, 0, stream>>>(ei, E, N, flags, cursor, csr);

    k_transpose<<<256, 256, 0, stream>>>(W, wt, flags);

    int mtiles = (N + 15) / 16;
    for (int l = 0; l < 2; l++) {
        const void* xin = (l == 0) ? x : (const void*)d_out;  // layer 1 reads layer-0 output (same dtype)
        k_gemm<<<mtiles, 256, 0, stream>>>(xin, wt + l * 32768, hbuf, N, flags);
        k_alpha<<<(N + 3) / 4, 256, 0, stream>>>(hbuf, atts, attd, l, flags, as_, ad_, N);
        k_aggregate<<<(N + 3) / 4, 256, 0, stream>>>(hbuf, as_, ad_, rowptr, csr, bias, l, flags,
                                                     d_out, N, EL);
    }
}